// Round 1
// baseline (34806.223 us; speedup 1.0000x reference)
//
#include <hip/hip_runtime.h>
#include <cstdint>

// HardLSTM: T=512 B=32 I=512 H=1024, 2 layers, bidirectional.
// Pipeline: cvt(fp32->fp16) -> GEMM gx0 -> persistent recurrent L0 ->
//           GEMM gx1 -> persistent recurrent L1.
// All matmuls fp16 MFMA (16x16x32), fp32 accumulate; c/h state fp32 in regs.

typedef _Float16 half8 __attribute__((ext_vector_type(8)));
typedef _Float16 half4v __attribute__((ext_vector_type(4)));
typedef float floatx4 __attribute__((ext_vector_type(4)));

#define T_LEN 512
#define BATCH 32
#define HID 1024
#define NTB 16384   // T*B

__device__ __forceinline__ float hsig(float x) {
  return fminf(fmaxf(fmaf(0.2f, x, 0.5f), 0.0f), 1.0f);
}
__device__ __forceinline__ float htanh(float x) {
  return fminf(fmaxf(x, -1.0f), 1.0f);
}

// global -> LDS direct copy, 16B/lane. LDS dest must be wave-uniform base;
// data lands at base + lane*16.
__device__ __forceinline__ void gll16(const void* g, void* l) {
  __builtin_amdgcn_global_load_lds((const __attribute__((address_space(1))) void*)g,
                                   (__attribute__((address_space(3))) void*)l,
                                   16, 0, 0);
}

__global__ __launch_bounds__(256) void cvt_f32_f16(const float* __restrict__ s,
                                                   _Float16* __restrict__ d,
                                                   int n4) {
  int i = blockIdx.x * blockDim.x + threadIdx.x;
  int stride = gridDim.x * blockDim.x;
  for (; i < n4; i += stride) {
    float4 v = ((const float4*)s)[i];
    half4v h = {(_Float16)v.x, (_Float16)v.y, (_Float16)v.z, (_Float16)v.w};
    ((half4v*)d)[i] = h;
  }
}

// C[M=8192][NTB] = A[M][K] * B[NTB][K]^T + bias[M], fp16 out.
// 128x128 tile, BK=64, 4 waves (each 64x64), T2 XOR-swizzled LDS via
// pre-swizzled global source (global_load_lds writes linearly).
__global__ __launch_bounds__(256) void gemm_gx(const _Float16* __restrict__ A,
                                               const _Float16* __restrict__ B,
                                               const float* __restrict__ bias,
                                               _Float16* __restrict__ C,
                                               int K) {
  __shared__ __align__(16) _Float16 A_s[128 * 64];
  __shared__ __align__(16) _Float16 B_s[128 * 64];
  const int tid = threadIdx.x;
  const int lane = tid & 63;
  const int w = tid >> 6;
  const int bm = blockIdx.x >> 7;   // M/128 = 64 blocks
  const int bn = blockIdx.x & 127;  // N/128 = 128 blocks
  const int m0 = bm * 128, n0 = bn * 128;

  floatx4 acc[4][4] = {};

  // staging: instr i of wave w covers rows i*32+w*8+(lane>>3), 16B chunk (lane&7)
  // source column chunk pre-swizzled: (lane&7) ^ (row&7), row&7 == (lane>>3)&7
  const int srow = w * 8 + (lane >> 3);
  const int scol = ((lane & 7) ^ ((lane >> 3) & 7)) * 8;
  const _Float16* Ag = A + (size_t)(m0 + srow) * K + scol;
  const _Float16* Bg = B + (size_t)(n0 + srow) * K + scol;
  char* As_base = (char*)A_s + (size_t)(w * 8) * 128;
  char* Bs_base = (char*)B_s + (size_t)(w * 8) * 128;

  const int wm = (w >> 1) * 64;
  const int wn = (w & 1) * 64;
  const int fr = lane & 15;   // fragment row/col
  const int fk = lane >> 4;   // k-group

  for (int kb = 0; kb < K; kb += 64) {
#pragma unroll
    for (int i = 0; i < 4; ++i) {
      gll16(Ag + (size_t)i * 32 * K + kb, As_base + i * 32 * 128);
      gll16(Bg + (size_t)i * 32 * K + kb, Bs_base + i * 32 * 128);
    }
    __syncthreads();
#pragma unroll
    for (int kt = 0; kt < 2; ++kt) {
      half8 af[4], bf[4];
#pragma unroll
      for (int mi = 0; mi < 4; ++mi) {
        int row = wm + mi * 16 + fr;
        int k8 = kt * 4 + fk;
        af[mi] = *(const half8*)(A_s + row * 64 + ((k8 ^ (row & 7)) << 3));
      }
#pragma unroll
      for (int ni = 0; ni < 4; ++ni) {
        int row = wn + ni * 16 + fr;
        int k8 = kt * 4 + fk;
        bf[ni] = *(const half8*)(B_s + row * 64 + ((k8 ^ (row & 7)) << 3));
      }
#pragma unroll
      for (int mi = 0; mi < 4; ++mi)
#pragma unroll
        for (int ni = 0; ni < 4; ++ni)
          acc[mi][ni] = __builtin_amdgcn_mfma_f32_16x16x32_f16(af[mi], bf[ni],
                                                               acc[mi][ni], 0, 0, 0);
    }
    __syncthreads();
  }

  // epilogue: D row = (lane>>4)*4 + reg, col = lane&15
#pragma unroll
  for (int mi = 0; mi < 4; ++mi) {
    int rowb = m0 + wm + mi * 16 + fk * 4;
#pragma unroll
    for (int r = 0; r < 4; ++r) {
      float bv = bias[rowb + r];
#pragma unroll
      for (int ni = 0; ni < 4; ++ni) {
        int col = n0 + wn + ni * 16 + fr;
        C[(size_t)(rowb + r) * NTB + col] = (_Float16)(acc[mi][ni][r] + bv);
      }
    }
  }
}

// Persistent bidirectional recurrence. Grid = 256 WGs x 256 thr.
// WGs [0,128): forward; [128,256): backward. Each WG owns 8 hidden units
// (32 gate rows). w_hh fragments live in registers (loaded once).
// Per step: stage h (global ping-pong -> LDS, XOR-swizzled), MFMA
// [32 gates x 32 batch x K=1024], gate nonlinearity, write h, flag barrier.
__global__ __launch_bounds__(256) void recur(const _Float16* __restrict__ gx,
                                             const _Float16* __restrict__ whh,
                                             const float* __restrict__ h0,
                                             const float* __restrict__ c0,
                                             _Float16* __restrict__ hbuf,
                                             int* __restrict__ flags,
                                             int layer,
                                             _Float16* __restrict__ yf16,
                                             float* __restrict__ yf32,
                                             float* __restrict__ hn,
                                             float* __restrict__ cn) {
  __shared__ __align__(16) _Float16 h_s[32 * 1024];  // 64KB, swizzled [b][k]
  float* gates_s = (float*)h_s;  // 4KB overlay, used only after h_s reads done

  const int tid = threadIdx.x;
  const int lane = tid & 63;
  const int w = tid >> 6;
  const int wm = w >> 1;  // gate-row tile (0: i/f rows, 1: g/o rows)
  const int wn = w & 1;   // batch tile
  const int dir = blockIdx.x >> 7;
  const int wgd = blockIdx.x & 127;
  const int u0 = wgd * 8;
  const int fr = lane & 15, fk = lane >> 4;

  // register-resident A fragments: slice row r = g*8+u', global row g*1024+u0+u'
  half8 afrag[32];
  {
    int r = wm * 16 + fr;
    int grow = dir * 4096 + (r >> 3) * 1024 + (u0 + (r & 7));
    const _Float16* wrow = whh + (size_t)grow * HID;
#pragma unroll
    for (int kt = 0; kt < 32; ++kt)
      afrag[kt] = *(const half8*)(wrow + kt * 32 + fk * 8);
  }

  // init ping buffer 0 with h0 (each WG writes the full dir copy; values identical)
  {
    const float* hs0 = h0 + (size_t)(layer * 2 + dir) * (BATCH * HID);
    _Float16* hdst = hbuf + (size_t)dir * (BATCH * HID);
    for (int i = tid; i < BATCH * HID; i += 256) hdst[i] = (_Float16)hs0[i];
  }
  const int eu = tid >> 5, eb = tid & 31;  // elementwise ownership: unit, batch
  float c = c0[(size_t)(layer * 2 + dir) * (BATCH * HID) + eb * HID + u0 + eu];
  __syncthreads();

  const size_t HB = (size_t)BATCH * HID;   // halves per dir buffer
  const size_t GS = (size_t)1024 * NTB;    // gx stride between gates
  const _Float16* gxb = gx + (size_t)(dir * 4096 + u0 + eu) * NTB;

  for (int t = 0; t < T_LEN; ++t) {
    const int p = t & 1;
    const _Float16* hsrc = hbuf + ((size_t)p * 2 + dir) * HB;

    // stage h: linear LDS dest, inverse-swizzled global source (slot ^= b&7)
#pragma unroll
    for (int i = 0; i < 16; ++i) {
      int cb = (i * 4 + w) * 64;  // wave-uniform chunk base
      int cc = cb + lane;
      int b = cc >> 7;
      int slot = cc & 127;
      int src = b * 128 + (slot ^ (b & 7));
      gll16(hsrc + (size_t)src * 8, (char*)h_s + (size_t)cb * 16);
    }

    // prefetch gx for this step (latency hides under staging drain)
    const int tseq = dir ? (T_LEN - 1 - t) : t;
    const size_t col = (size_t)tseq * BATCH + eb;
    float gxi = (float)gxb[0 * GS + col];
    float gxf = (float)gxb[1 * GS + col];
    float gxg = (float)gxb[2 * GS + col];
    float gxo = (float)gxb[3 * GS + col];

    __syncthreads();  // drains gll + prefetch (vmcnt 0 before barrier)

    floatx4 acc = {0.f, 0.f, 0.f, 0.f};
    const int brow = wn * 16 + fr;
    const int bswz = brow & 7;
    const _Float16* hp = h_s + brow * HID;
#pragma unroll
    for (int kt = 0; kt < 32; ++kt) {
      int k8 = kt * 4 + fk;
      half8 bfr = *(const half8*)(hp + ((k8 ^ bswz) << 3));
      acc = __builtin_amdgcn_mfma_f32_16x16x32_f16(afrag[kt], bfr, acc, 0, 0, 0);
    }
    __syncthreads();  // all h_s reads done before gates overlay write
    {
      int rbase = wm * 16 + fk * 4;
#pragma unroll
      for (int r = 0; r < 4; ++r)
        gates_s[(rbase + r) * 32 + wn * 16 + fr] = acc[r];
    }
    __syncthreads();

    float ip = gates_s[(0 + eu) * 32 + eb] + gxi;
    float fp = gates_s[(8 + eu) * 32 + eb] + gxf;
    float gp = gates_s[(16 + eu) * 32 + eb] + gxg;
    float op = gates_s[(24 + eu) * 32 + eb] + gxo;
    float ig = hsig(ip), fg = hsig(fp), gg = htanh(gp), og = hsig(op);
    c = fg * c + ig * gg;
    float h = og * htanh(c);

    hbuf[(((size_t)(p ^ 1)) * 2 + dir) * HB + eb * HID + u0 + eu] = (_Float16)h;
    size_t yidx = ((size_t)tseq * BATCH + eb) * 2048 + dir * 1024 + u0 + eu;
    if (yf16) yf16[yidx] = (_Float16)h;
    else      yf32[yidx] = h;

    if (t == T_LEN - 1) {
      size_t o = (size_t)(layer * 2 + dir) * (BATCH * HID) + eb * HID + u0 + eu;
      hn[o] = h;
      cn[o] = c;
    } else {
      // per-direction grid barrier: release flag store + 64-lane poll
      int* fl = flags + dir * 128;
      __syncthreads();  // drains this WG's h stores
      if (tid == 0) {
        __threadfence();
        __hip_atomic_store(fl + wgd, t + 1, __ATOMIC_RELEASE, __HIP_MEMORY_SCOPE_AGENT);
      }
      if (tid < 64) {
        for (;;) {
          int v0 = __hip_atomic_load(fl + tid, __ATOMIC_RELAXED, __HIP_MEMORY_SCOPE_AGENT);
          int v1 = __hip_atomic_load(fl + 64 + tid, __ATOMIC_RELAXED, __HIP_MEMORY_SCOPE_AGENT);
          if (__all((v0 >= t + 1) && (v1 >= t + 1))) break;
          __builtin_amdgcn_s_sleep(1);
        }
      }
      __syncthreads();
      __threadfence();  // acquire: later h_s staging must see remote h stores
    }
  }
}

extern "C" void kernel_launch(void* const* d_in, const int* in_sizes, int n_in,
                              void* d_out, int out_size, void* d_ws, size_t ws_size,
                              hipStream_t stream) {
  const float* x    = (const float*)d_in[0];
  const float* h0   = (const float*)d_in[1];
  const float* c0   = (const float*)d_in[2];
  const float* wih0 = (const float*)d_in[3];
  const float* whh0 = (const float*)d_in[4];
  const float* b0   = (const float*)d_in[5];
  const float* wih1 = (const float*)d_in[6];
  const float* whh1 = (const float*)d_in[7];
  const float* b1   = (const float*)d_in[8];
  float* out = (float*)d_out;

  // workspace carve-up (~408 MB)
  char* ws = (char*)d_ws;
  size_t off = 0;
  int* flags = (int*)ws;                      off += 4096;
  _Float16* xh    = (_Float16*)(ws + off);    off += (size_t)8388608 * 2;
  _Float16* wih0h = (_Float16*)(ws + off);    off += (size_t)4194304 * 2;
  _Float16* whh0h = (_Float16*)(ws + off);    off += (size_t)8388608 * 2;
  _Float16* wih1h = (_Float16*)(ws + off);    off += (size_t)16777216 * 2;
  _Float16* whh1h = (_Float16*)(ws + off);    off += (size_t)8388608 * 2;
  _Float16* y0h   = (_Float16*)(ws + off);    off += (size_t)33554432 * 2;
  _Float16* hbuf  = (_Float16*)(ws + off);    off += (size_t)131072 * 2;
  _Float16* gxbuf = (_Float16*)(ws + off);    off += (size_t)134217728 * 2;

  hipMemsetAsync(flags, 0, 4096, stream);

  cvt_f32_f16<<<2048, 256, 0, stream>>>(x,    xh,    8388608 / 4);
  cvt_f32_f16<<<2048, 256, 0, stream>>>(wih0, wih0h, 4194304 / 4);
  cvt_f32_f16<<<2048, 256, 0, stream>>>(whh0, whh0h, 8388608 / 4);
  cvt_f32_f16<<<2048, 256, 0, stream>>>(wih1, wih1h, 16777216 / 4);
  cvt_f32_f16<<<2048, 256, 0, stream>>>(whh1, whh1h, 8388608 / 4);

  float* hn = out + 33554432;
  float* cn = out + 33685504;

  // layer 0
  gemm_gx<<<8192, 256, 0, stream>>>(wih0h, xh, b0, gxbuf, 512);
  recur<<<256, 256, 0, stream>>>(gxbuf, whh0h, h0, c0, hbuf, flags, 0,
                                 y0h, nullptr, hn, cn);
  // layer 1
  gemm_gx<<<8192, 256, 0, stream>>>(wih1h, y0h, b1, gxbuf, 2048);
  recur<<<256, 256, 0, stream>>>(gxbuf, whh1h, h0, c0, hbuf, flags + 256, 1,
                                 nullptr, out, hn, cn);
}

// Round 2
// 6651.208 us; speedup vs baseline: 5.2331x; 5.2331x over previous
//
#include <hip/hip_runtime.h>
#include <cstdint>

// HardLSTM: T=512 B=32 I=512 H=1024, 2 layers, bidirectional.
// cvt(fp32->fp16) -> GEMM gx0 -> persistent recur L0 -> GEMM gx1 -> recur L1.
// Recurrence exchanges h through L3 via sc0|sc1 (coherent) loads/stores only —
// no device fences, no L2 writeback/invalidate.

typedef _Float16 half8 __attribute__((ext_vector_type(8)));
typedef _Float16 half4v __attribute__((ext_vector_type(4)));
typedef float floatx4 __attribute__((ext_vector_type(4)));
typedef int int4v __attribute__((ext_vector_type(4)));

#define T_LEN 512
#define BATCH 32
#define HID 1024
#define NTB 16384   // T*B
#define UPW 16      // hidden units per WG
#define WPD 64      // WGs per direction

__device__ __forceinline__ float hsig(float x) {
  return fminf(fmaxf(fmaf(0.2f, x, 0.5f), 0.0f), 1.0f);
}
__device__ __forceinline__ float htanh(float x) {
  return fminf(fmaxf(x, -1.0f), 1.0f);
}

// Coherent (cross-XCD) 16B load/store: bypass L1+L2, served at L3.
__device__ __forceinline__ int4v load_co16(const void* p) {
  int4v r;
  asm volatile("global_load_dwordx4 %0, %1, off sc0 sc1"
               : "=&v"(r) : "v"(p) : "memory");
  return r;
}
__device__ __forceinline__ void store_co16(void* p, int4v v) {
  asm volatile("global_store_dwordx4 %0, %1, off sc0 sc1"
               :: "v"(p), "v"(v) : "memory");
}
__device__ __forceinline__ void waitcnt0() {
  asm volatile("s_waitcnt vmcnt(0)" ::: "memory");
}

// global -> LDS direct copy, 16B/lane (GEMM staging only).
__device__ __forceinline__ void gll16(const void* g, void* l) {
  __builtin_amdgcn_global_load_lds((const __attribute__((address_space(1))) void*)g,
                                   (__attribute__((address_space(3))) void*)l,
                                   16, 0, 0);
}

__global__ __launch_bounds__(256) void cvt_f32_f16(const float* __restrict__ s,
                                                   _Float16* __restrict__ d,
                                                   int n4) {
  int i = blockIdx.x * blockDim.x + threadIdx.x;
  int stride = gridDim.x * blockDim.x;
  for (; i < n4; i += stride) {
    float4 v = ((const float4*)s)[i];
    half4v h = {(_Float16)v.x, (_Float16)v.y, (_Float16)v.z, (_Float16)v.w};
    ((half4v*)d)[i] = h;
  }
}

// C[M=8192][NTB] = A[M][K] * B[NTB][K]^T + bias[M], fp16 out. (unchanged)
__global__ __launch_bounds__(256) void gemm_gx(const _Float16* __restrict__ A,
                                               const _Float16* __restrict__ B,
                                               const float* __restrict__ bias,
                                               _Float16* __restrict__ C,
                                               int K) {
  __shared__ __align__(16) _Float16 A_s[128 * 64];
  __shared__ __align__(16) _Float16 B_s[128 * 64];
  const int tid = threadIdx.x;
  const int lane = tid & 63;
  const int w = tid >> 6;
  const int bm = blockIdx.x >> 7;
  const int bn = blockIdx.x & 127;
  const int m0 = bm * 128, n0 = bn * 128;

  floatx4 acc[4][4] = {};

  const int srow = w * 8 + (lane >> 3);
  const int scol = ((lane & 7) ^ ((lane >> 3) & 7)) * 8;
  const _Float16* Ag = A + (size_t)(m0 + srow) * K + scol;
  const _Float16* Bg = B + (size_t)(n0 + srow) * K + scol;
  char* As_base = (char*)A_s + (size_t)(w * 8) * 128;
  char* Bs_base = (char*)B_s + (size_t)(w * 8) * 128;

  const int wm = (w >> 1) * 64;
  const int wn = (w & 1) * 64;
  const int fr = lane & 15;
  const int fk = lane >> 4;

  for (int kb = 0; kb < K; kb += 64) {
#pragma unroll
    for (int i = 0; i < 4; ++i) {
      gll16(Ag + (size_t)i * 32 * K + kb, As_base + i * 32 * 128);
      gll16(Bg + (size_t)i * 32 * K + kb, Bs_base + i * 32 * 128);
    }
    __syncthreads();
#pragma unroll
    for (int kt = 0; kt < 2; ++kt) {
      half8 af[4], bf[4];
#pragma unroll
      for (int mi = 0; mi < 4; ++mi) {
        int row = wm + mi * 16 + fr;
        int k8 = kt * 4 + fk;
        af[mi] = *(const half8*)(A_s + row * 64 + ((k8 ^ (row & 7)) << 3));
      }
#pragma unroll
      for (int ni = 0; ni < 4; ++ni) {
        int row = wn + ni * 16 + fr;
        int k8 = kt * 4 + fk;
        bf[ni] = *(const half8*)(B_s + row * 64 + ((k8 ^ (row & 7)) << 3));
      }
#pragma unroll
      for (int mi = 0; mi < 4; ++mi)
#pragma unroll
        for (int ni = 0; ni < 4; ++ni)
          acc[mi][ni] = __builtin_amdgcn_mfma_f32_16x16x32_f16(af[mi], bf[ni],
                                                               acc[mi][ni], 0, 0, 0);
    }
    __syncthreads();
  }

#pragma unroll
  for (int mi = 0; mi < 4; ++mi) {
    int rowb = m0 + wm + mi * 16 + fk * 4;
#pragma unroll
    for (int r = 0; r < 4; ++r) {
      float bv = bias[rowb + r];
#pragma unroll
      for (int ni = 0; ni < 4; ++ni) {
        int col = n0 + wn + ni * 16 + fr;
        C[(size_t)(rowb + r) * NTB + col] = (_Float16)(acc[mi][ni][r] + bv);
      }
    }
  }
}

// Persistent bidirectional recurrence. Grid = 128 WGs x 512 thr (1 WG/CU-ish).
// WG owns 16 hidden units (64 gate rows). w_hh fragments register-resident.
// h exchanged via coherent (sc0 sc1) L3 accesses; flags likewise; NO fences.
__global__ __launch_bounds__(512) void recur(const _Float16* __restrict__ gx,
                                             const _Float16* __restrict__ whh,
                                             const float* __restrict__ h0,
                                             const float* __restrict__ c0,
                                             _Float16* __restrict__ hbuf,
                                             int* __restrict__ flags,
                                             int layer,
                                             _Float16* __restrict__ yf16,
                                             float* __restrict__ yf32,
                                             float* __restrict__ hn,
                                             float* __restrict__ cn) {
  __shared__ __align__(16) _Float16 h_s[BATCH * HID];   // 64KB, swizzled [b][k]
  __shared__ float gates_s[64 * 33];                    // padded stride
  __shared__ __align__(16) _Float16 hout_s[BATCH * UPW];

  const int tid = threadIdx.x;
  const int lane = tid & 63;
  const int w = tid >> 6;        // 8 waves
  const int g = w >> 1;          // gate (i,f,g,o)
  const int wn = w & 1;          // batch half
  const int dir = blockIdx.x >> 6;
  const int wgd = blockIdx.x & 63;
  const int u0 = wgd * UPW;
  const int fr = lane & 15, fk = lane >> 4;

  // register-resident A fragments: 16 gate rows (gate g) x K=1024
  half8 af[32];
  {
    const _Float16* wrow = whh + ((size_t)dir * 4096 + g * 1024 + u0 + fr) * HID;
#pragma unroll
    for (int kt = 0; kt < 32; ++kt)
      af[kt] = *(const half8*)(wrow + kt * 32 + fk * 8);
  }

  const int eb = tid & 31, eu = tid >> 5;   // elementwise: batch, unit
  const size_t st0 = (size_t)(layer * 2 + dir) * (BATCH * HID);
  float c = c0[st0 + eb * HID + u0 + eu];

  _Float16* buf0 = hbuf + (size_t)dir * (BATCH * HID);
  _Float16* buf1 = hbuf + (size_t)(2 + dir) * (BATCH * HID);
  int* fl = flags + dir * WPD;

  // init: coherent-write this WG's h0 slice into buf0, then flag=1
  hout_s[eb * UPW + eu] = (_Float16)h0[st0 + eb * HID + u0 + eu];
  __syncthreads();
  if (w == 0) {
    int b = lane >> 1, hf = lane & 1;
    int4v v = *(const int4v*)(hout_s + b * UPW + hf * 8);
    store_co16(buf0 + (size_t)b * HID + u0 + hf * 8, v);
    waitcnt0();
    if (lane == 0) {
      int fv = 1;
      asm volatile("global_store_dword %0, %1, off sc0 sc1"
                   :: "v"(fl + wgd), "v"(fv) : "memory");
    }
  }

  const size_t GS = (size_t)1024 * NTB;
  const _Float16* gxb = gx + ((size_t)dir * 4096 + u0 + eu) * NTB;

  for (int t = 0; t < T_LEN; ++t) {
    // barrier: wait until all WGs of this dir published h(t-1)
    if (w == 0) {
      const int want = t + 1;
      for (;;) {
        int v;
        asm volatile("global_load_dword %0, %1, off sc0 sc1\n\ts_waitcnt vmcnt(0)"
                     : "=&v"(v) : "v"(fl + lane) : "memory");
        if (__all(v >= want)) break;
        __builtin_amdgcn_s_sleep(1);
      }
    }
    __syncthreads();

    const _Float16* src = (t & 1) ? buf1 : buf0;
    _Float16* dst = (t & 1) ? buf0 : buf1;

    // stage h(t-1): 64KB coherent load -> regs -> swizzled LDS
    int4v hv[8];
#pragma unroll
    for (int i = 0; i < 8; ++i)
      hv[i] = load_co16((const char*)src + (size_t)(i * 512 + tid) * 16);
    waitcnt0();
#pragma unroll
    for (int i = 0; i < 8; ++i) {
      int cbyte = (i * 512 + tid) * 16;
      int b = cbyte >> 11;
      int slot = cbyte & 2047;
      *(int4v*)((char*)h_s + b * 2048 + (slot ^ ((b & 7) << 4))) = hv[i];
    }

    // gx prefetch (plain cached loads; latency hides under barrier+MFMA)
    const int tseq = dir ? (T_LEN - 1 - t) : t;
    const size_t col = (size_t)tseq * BATCH + eb;
    float gxi = (float)gxb[0 * GS + col];
    float gxf = (float)gxb[1 * GS + col];
    float gxg = (float)gxb[2 * GS + col];
    float gxo = (float)gxb[3 * GS + col];

    __syncthreads();  // h_s ready

    // MFMA: gates[g][16 units x 16 batch] over K=1024, two chains
    floatx4 acc0 = {0.f, 0.f, 0.f, 0.f}, acc1 = {0.f, 0.f, 0.f, 0.f};
    {
      const int b = wn * 16 + fr;
      const char* hp = (const char*)h_s + b * 2048;
      const int bx = (b & 7) << 4;
#pragma unroll
      for (int kt = 0; kt < 32; kt += 2) {
        half8 b0 = *(const half8*)(hp + ((kt * 64 + fk * 16) ^ bx));
        half8 b1 = *(const half8*)(hp + (((kt + 1) * 64 + fk * 16) ^ bx));
        acc0 = __builtin_amdgcn_mfma_f32_16x16x32_f16(af[kt], b0, acc0, 0, 0, 0);
        acc1 = __builtin_amdgcn_mfma_f32_16x16x32_f16(af[kt + 1], b1, acc1, 0, 0, 0);
      }
    }
    floatx4 acc = acc0 + acc1;
#pragma unroll
    for (int r = 0; r < 4; ++r)
      gates_s[(g * 16 + fk * 4 + r) * 33 + wn * 16 + fr] = acc[r];
    __syncthreads();

    float ip = gates_s[(0 * 16 + eu) * 33 + eb] + gxi;
    float fp = gates_s[(1 * 16 + eu) * 33 + eb] + gxf;
    float gp = gates_s[(2 * 16 + eu) * 33 + eb] + gxg;
    float op = gates_s[(3 * 16 + eu) * 33 + eb] + gxo;
    float ig = hsig(ip), fg = hsig(fp), gg = htanh(gp), og = hsig(op);
    c = fg * c + ig * gg;
    float h = og * htanh(c);

    size_t yidx = ((size_t)tseq * BATCH + eb) * 2048 + (size_t)dir * 1024 + u0 + eu;
    if (yf16) yf16[yidx] = (_Float16)h;
    else      yf32[yidx] = h;

    hout_s[eb * UPW + eu] = (_Float16)h;

    if (t == T_LEN - 1) {
      size_t o = st0 + eb * HID + u0 + eu;
      hn[o] = h;
      cn[o] = c;
    } else {
      __syncthreads();  // hout_s ready
      if (w == 0) {
        int b = lane >> 1, hf = lane & 1;
        int4v v = *(const int4v*)(hout_s + b * UPW + hf * 8);
        store_co16(dst + (size_t)b * HID + u0 + hf * 8, v);
        waitcnt0();
        if (lane == 0) {
          int fv = t + 2;
          asm volatile("global_store_dword %0, %1, off sc0 sc1"
                       :: "v"(fl + wgd), "v"(fv) : "memory");
        }
      }
      // non-zero waves run ahead to the next top __syncthreads
    }
  }
}

extern "C" void kernel_launch(void* const* d_in, const int* in_sizes, int n_in,
                              void* d_out, int out_size, void* d_ws, size_t ws_size,
                              hipStream_t stream) {
  const float* x    = (const float*)d_in[0];
  const float* h0   = (const float*)d_in[1];
  const float* c0   = (const float*)d_in[2];
  const float* wih0 = (const float*)d_in[3];
  const float* whh0 = (const float*)d_in[4];
  const float* b0   = (const float*)d_in[5];
  const float* wih1 = (const float*)d_in[6];
  const float* whh1 = (const float*)d_in[7];
  const float* b1   = (const float*)d_in[8];
  float* out = (float*)d_out;

  char* ws = (char*)d_ws;
  size_t off = 0;
  int* flags = (int*)ws;                      off += 4096;
  _Float16* xh    = (_Float16*)(ws + off);    off += (size_t)8388608 * 2;
  _Float16* wih0h = (_Float16*)(ws + off);    off += (size_t)4194304 * 2;
  _Float16* whh0h = (_Float16*)(ws + off);    off += (size_t)8388608 * 2;
  _Float16* wih1h = (_Float16*)(ws + off);    off += (size_t)16777216 * 2;
  _Float16* whh1h = (_Float16*)(ws + off);    off += (size_t)8388608 * 2;
  _Float16* y0h   = (_Float16*)(ws + off);    off += (size_t)33554432 * 2;
  _Float16* hbuf  = (_Float16*)(ws + off);    off += (size_t)131072 * 2;
  _Float16* gxbuf = (_Float16*)(ws + off);    off += (size_t)134217728 * 2;

  hipMemsetAsync(flags, 0, 4096, stream);

  cvt_f32_f16<<<2048, 256, 0, stream>>>(x,    xh,    8388608 / 4);
  cvt_f32_f16<<<2048, 256, 0, stream>>>(wih0, wih0h, 4194304 / 4);
  cvt_f32_f16<<<2048, 256, 0, stream>>>(whh0, whh0h, 8388608 / 4);
  cvt_f32_f16<<<2048, 256, 0, stream>>>(wih1, wih1h, 16777216 / 4);
  cvt_f32_f16<<<2048, 256, 0, stream>>>(whh1, whh1h, 8388608 / 4);

  float* hn = out + 33554432;
  float* cn = out + 33685504;

  // layer 0
  gemm_gx<<<8192, 256, 0, stream>>>(wih0h, xh, b0, gxbuf, 512);
  recur<<<128, 512, 0, stream>>>(gxbuf, whh0h, h0, c0, hbuf, flags, 0,
                                 y0h, nullptr, hn, cn);
  // layer 1
  gemm_gx<<<8192, 256, 0, stream>>>(wih1h, y0h, b1, gxbuf, 2048);
  recur<<<128, 512, 0, stream>>>(gxbuf, whh1h, h0, c0, hbuf, flags + 128, 1,
                                 nullptr, out, hn, cn);
}